// Round 4
// baseline (10387.679 us; speedup 1.0000x reference)
//
#include <hip/hip_runtime.h>
#include <hip/hip_bf16.h>

typedef short short8 __attribute__((ext_vector_type(8)));
typedef short short4v __attribute__((ext_vector_type(4)));
typedef float f32x4 __attribute__((ext_vector_type(4)));
typedef __bf16 bf16x8 __attribute__((ext_vector_type(8)));

#define DEVI static __device__ __forceinline__

#if __has_builtin(__builtin_amdgcn_exp2f)
#define EXP2(x) __builtin_amdgcn_exp2f(x)
#else
#define EXP2(x) exp2f(x)
#endif
#if __has_builtin(__builtin_amdgcn_rcpf)
#define RCP(x) __builtin_amdgcn_rcpf(x)
#else
#define RCP(x) (1.0f / (x))
#endif

static constexpr int BB = 256, TT = 512, DIN0 = 40, HH = 128, NCLS = 7;
static constexpr int NB = 16;     // batch rows per workgroup
static constexpr int NTHR = 512;  // 8 waves
static constexpr float L2E = 1.44269504088896f;

DEVI short f2b(float x) {
  union { __hip_bfloat16 h; short s; } u;
  u.h = __float2bfloat16(x);
  return u.s;
}

DEVI bf16x8 as_bf(short8 s) { return __builtin_bit_cast(bf16x8, s); }

// ===================== REAL PATH: Round-1 kernel, verbatim =====================
template <bool L0>
__global__ __launch_bounds__(NTHR, 2) void lstm_kernel(
    const float* __restrict__ x0, const short* __restrict__ h1_in,
    const float* __restrict__ Wih_f, const float* __restrict__ Whh_f,
    const float* __restrict__ bias_f, const float* __restrict__ Wih_r,
    const float* __restrict__ Whh_r, const float* __restrict__ bias_r,
    short* __restrict__ h1_out, float* __restrict__ h2last) {
  constexpr int K0 = L0 ? 64 : 256;   // padded x-part of K
  constexpr int DI = L0 ? DIN0 : 256; // real x dim
  constexpr int KT = K0 + HH;         // total K (192 / 384)
  constexpr int KF = KT / 32;         // k-fragments (6 / 12)
  constexpr int RS = KT + 8;          // LDS row stride

  __shared__ short Bbuf[2][NB][RS];

  const int tid = threadIdx.x;
  const int w = tid >> 6;
  const int lane = tid & 63;
  const int lg = lane >> 4;
  const int bcol = lane & 15;
  const int dir = blockIdx.x & 1;
  const int b0 = (blockIdx.x >> 1) * NB;

  const float* __restrict__ Wih = dir ? Wih_r : Wih_f;
  const float* __restrict__ Whh = dir ? Whh_r : Whh_f;
  const float* __restrict__ bias = dir ? bias_r : bias_f;

  short8 wfrag[4][KF];
#pragma unroll
  for (int q = 0; q < 4; ++q) {
    const float scale = (q == 2) ? (2.0f * L2E) : (-L2E);
    const int m = q * HH + w * 16 + bcol;
#pragma unroll
    for (int kk = 0; kk < KF; ++kk) {
      short8 f;
#pragma unroll
      for (int e = 0; e < 8; ++e) {
        const int k = kk * 32 + lg * 8 + e;
        float v = 0.0f;
        if (k < K0) {
          if (k < DI) v = Wih[(size_t)m * DI + k];
        } else {
          v = Whh[(size_t)m * HH + (k - K0)];
        }
        f[e] = f2b(v * scale);
      }
      wfrag[q][kk] = f;
    }
  }

  f32x4 bq[4];
#pragma unroll
  for (int q = 0; q < 4; ++q) {
    const float scale = (q == 2) ? (2.0f * L2E) : (-L2E);
#pragma unroll
    for (int r = 0; r < 4; ++r)
      bq[q][r] = bias[q * HH + w * 16 + lg * 4 + r] * scale;
  }

  for (int i = tid; i < 2 * NB * RS; i += NTHR) (&Bbuf[0][0][0])[i] = 0;
  __syncthreads();

  {
    const int t0 = dir ? (TT - 1) : 0;
    if constexpr (L0) {
      if (tid < 160) {
        const int bl = tid / 10, c4 = tid % 10;
        f32x4 v = *(const f32x4*)(x0 + ((size_t)(b0 + bl) * TT + t0) * DI + c4 * 4);
        short4v o;
        o[0] = f2b(v[0]); o[1] = f2b(v[1]); o[2] = f2b(v[2]); o[3] = f2b(v[3]);
        *(short4v*)&Bbuf[0][bl][c4 * 4] = o;
      }
    } else {
      const int bl = tid >> 5, seg = tid & 31;
      short8 v = *(const short8*)(h1_in + ((size_t)(b0 + bl) * TT + t0) * 256 + seg * 8);
      *(short8*)&Bbuf[0][bl][seg * 8] = v;
    }
  }
  __syncthreads();

  f32x4 cst = {0.f, 0.f, 0.f, 0.f};

  for (int s = 0; s < TT; ++s) {
    const int cur = s & 1;
    const int t = dir ? (TT - 1 - s) : s;
    const bool st = (s + 1 < TT);

    f32x4 xf;
    short8 xh;
    if (st) {
      const int tn = dir ? (TT - 2 - s) : (s + 1);
      if constexpr (L0) {
        if (tid < 160)
          xf = *(const f32x4*)(x0 + ((size_t)(b0 + tid / 10) * TT + tn) * DI + (tid % 10) * 4);
      } else {
        xh = *(const short8*)(h1_in + ((size_t)(b0 + (tid >> 5)) * TT + tn) * 256 + (tid & 31) * 8);
      }
    }

    f32x4 acc[4] = {bq[0], bq[1], bq[2], bq[3]};
#pragma unroll
    for (int kk = 0; kk < KF; ++kk) {
      const bf16x8 bf = as_bf(*(const short8*)&Bbuf[cur][bcol][kk * 32 + lg * 8]);
#pragma unroll
      for (int q = 0; q < 4; ++q)
        acc[q] = __builtin_amdgcn_mfma_f32_16x16x32_bf16(as_bf(wfrag[q][kk]), bf, acc[q], 0, 0, 0);
    }

    if (st) {
      if constexpr (L0) {
        if (tid < 160) {
          short4v o;
          o[0] = f2b(xf[0]); o[1] = f2b(xf[1]); o[2] = f2b(xf[2]); o[3] = f2b(xf[3]);
          *(short4v*)&Bbuf[cur ^ 1][tid / 10][(tid % 10) * 4] = o;
        }
      } else {
        *(short8*)&Bbuf[cur ^ 1][tid >> 5][(tid & 31) * 8] = xh;
      }
    }

    short4v hp;
    f32x4 hf;
#pragma unroll
    for (int r = 0; r < 4; ++r) {
      const float ig = RCP(1.0f + EXP2(acc[0][r]));
      const float fg = RCP(1.0f + EXP2(acc[1][r]));
      float tg = EXP2(acc[2][r]);
      tg = 1.0f - 2.0f * RCP(tg + 1.0f);
      const float og = RCP(1.0f + EXP2(acc[3][r]));
      const float cn = fg * cst[r] + ig * tg;
      cst[r] = cn;
      float tc = EXP2(cn * (2.0f * L2E));
      tc = 1.0f - 2.0f * RCP(tc + 1.0f);
      const float hv = og * tc;
      hf[r] = hv;
      hp[r] = f2b(hv);
    }
    const int j0 = w * 16 + lg * 4;
    *(short4v*)&Bbuf[cur ^ 1][bcol][K0 + j0] = hp;

    if constexpr (L0) {
      *(short4v*)(h1_out + (((size_t)(b0 + bcol) * TT + t) * 256) + dir * HH + j0) = hp;
    } else {
      if ((dir == 0 && s == TT - 1) || (dir == 1 && s == 0)) {
        *(f32x4*)(h2last + (size_t)(b0 + bcol) * 256 + dir * HH + j0) = hf;
      }
    }
    __syncthreads();
  }
}

__global__ void fc_kernel(const float* __restrict__ h2last,
                          const float* __restrict__ fcw,
                          const float* __restrict__ fcb,
                          float* __restrict__ out) {
  const int gid = blockIdx.x * blockDim.x + threadIdx.x;
  if (gid >= BB * NCLS) return;
  const int b = gid / NCLS, n = gid % NCLS;
  const float* hp = h2last + (size_t)b * 256;
  const float* wp = fcw + (size_t)n * 256;
  float s = fcb[n];
#pragma unroll 8
  for (int j = 0; j < 256; ++j) s = fmaf(hp[j], wp[j], s);
  out[gid] = s;
}

// ===================== DIAGNOSTIC PROBES (write only to dead scratch) =====================

// D1: effective-clock probe. 8192*64 = 524288 serial dependent v_fma_f32
// (~4 cyc dep latency => ~2.1M cycles). dur_us => SCLK. ~875us @ 2.4GHz.
__global__ void diag_clock(const float* __restrict__ xg, float* __restrict__ sink) {
  const int tid = threadIdx.x;
  float a = xg[tid & 63] * 0.1f;   // |a|<~0.4 -> chain converges, no overflow
  float b = xg[64 + (tid & 63)];
  float x = b;
  for (int i = 0; i < 8192; ++i) {
#pragma unroll
    for (int u = 0; u < 64; ++u) x = fmaf(x, a, b);
  }
  if (x == 1.2345e30f) sink[1] = x;  // never true; keeps chain live
}

// D2: step-skeleton probe. 8192 iterations of the R1 step's sync structure:
// 8x ds_read_b128 + ds_write_b64 + 8B global store + 16B global load +
// full __syncthreads() (vmcnt+lgkm drain). No math. Per-iter dur = skeleton cost.
__global__ __launch_bounds__(512, 2) void diag_sync(const float* __restrict__ xg,
                                                    long* __restrict__ gsink) {
  __shared__ short Bb[2][16][200];
  const int tid = threadIdx.x, lane = tid & 63, w = tid >> 6;
  const int lg = lane >> 4, bcol = lane & 15;
  for (int i = tid; i < 3200; i += 512) ((int*)&Bb[0][0][0])[i] = i * 1315423911;
  __syncthreads();
  int acc = 0;
  f32x4 xf = {0.f, 0.f, 0.f, 0.f};
  for (int s = 0; s < 8192; ++s) {
    const int cur = s & 1;
    int v = __float_as_int(xf[0]) ^ __float_as_int(xf[3]);
    xf = *(const f32x4*)(xg + (((s + 1) & 1023) * 2048 + tid * 4));  // < 5.2M floats
#pragma unroll
    for (int kk = 0; kk < 8; ++kk) {
      short8 r = *(const short8*)&Bb[cur][bcol][kk * 24 + lg * 8];
      v ^= (r[0] ^ r[1] ^ r[2] ^ r[3] ^ r[4] ^ r[5] ^ r[6] ^ r[7]);
    }
    acc ^= v;
    short4v wv;
    wv[0] = (short)v; wv[1] = (short)(v >> 8); wv[2] = (short)acc; wv[3] = (short)s;
    *(short4v*)&Bb[cur ^ 1][bcol][64 + w * 16 + lg * 4] = wv;
    gsink[tid] = ((long)acc << 32) | (unsigned)v;  // 8B store, drained by barrier
    __syncthreads();
  }
  if (acc == 0x12345678) gsink[512] = 1;
}

// D3: transcendental-chain probe. 8192 iterations of the exact R1 cell update
// (20 exp2 + 20 rcp per thread per iter), serial h->a->h chain, no LDS/barrier.
__global__ __launch_bounds__(512, 2) void diag_trans(const float* __restrict__ xg,
                                                     float* __restrict__ sink) {
  const int tid = threadIdx.x;
  f32x4 cst, h, k0, k1;
#pragma unroll
  for (int r = 0; r < 4; ++r) {
    cst[r] = xg[(tid + r * 64) & 4095] * 0.1f;
    h[r] = xg[(tid + r * 64 + 256) & 4095] * 0.1f;
    k0[r] = xg[(tid + r * 64 + 512) & 4095];
    k1[r] = xg[(tid + r * 64 + 768) & 4095];
  }
  for (int s = 0; s < 8192; ++s) {
    f32x4 a0 = h * k0 + cst;
    f32x4 a1 = h * k1 - cst;
    f32x4 a2 = cst * k0 - h;
    f32x4 a3 = cst * k1 + h;
#pragma unroll
    for (int r = 0; r < 4; ++r) {
      const float ig = RCP(1.0f + EXP2(a0[r]));
      const float fg = RCP(1.0f + EXP2(a1[r]));
      float tg = EXP2(a2[r]);
      tg = 1.0f - 2.0f * RCP(tg + 1.0f);
      const float og = RCP(1.0f + EXP2(a3[r]));
      float cn = fg * cst[r] + ig * tg;
      cn = fminf(fmaxf(cn, -10.f), 10.f);
      cst[r] = cn;
      float tc = EXP2(cn * (2.0f * L2E));
      tc = 1.0f - 2.0f * RCP(tc + 1.0f);
      h[r] = og * tc;
    }
  }
  if (h[0] == 42.f) sink[0] = h[0];
}

extern "C" void kernel_launch(void* const* d_in, const int* in_sizes, int n_in,
                              void* d_out, int out_size, void* d_ws, size_t ws_size,
                              hipStream_t stream) {
  const float* x     = (const float*)d_in[0];
  const float* Wih0f = (const float*)d_in[1];
  const float* Whh0f = (const float*)d_in[2];
  const float* b0f   = (const float*)d_in[3];
  const float* Wih0r = (const float*)d_in[4];
  const float* Whh0r = (const float*)d_in[5];
  const float* b0r   = (const float*)d_in[6];
  const float* Wih1f = (const float*)d_in[7];
  const float* Whh1f = (const float*)d_in[8];
  const float* b1f   = (const float*)d_in[9];
  const float* Wih1r = (const float*)d_in[10];
  const float* Whh1r = (const float*)d_in[11];
  const float* b1r   = (const float*)d_in[12];
  const float* fcw   = (const float*)d_in[13];
  const float* fcb   = (const float*)d_in[14];

  short* h1 = (short*)d_ws;                                           // [B][T][256] bf16, 64 MB
  float* h2last = (float*)((char*)d_ws + (size_t)BB * TT * 256 * 2);  // [B][256] f32
  // dead scratch for probes, beyond the real footprint (64MB + 256KB):
  float* dead = (float*)((char*)d_ws + (64u << 20) + (512u << 10));
  long* gsink = (long*)((char*)d_ws + (64u << 20) + (600u << 10));

  lstm_kernel<true><<<dim3(32), dim3(NTHR), 0, stream>>>(
      x, nullptr, Wih0f, Whh0f, b0f, Wih0r, Whh0r, b0r, h1, nullptr);
  lstm_kernel<false><<<dim3(32), dim3(NTHR), 0, stream>>>(
      nullptr, h1, Wih1f, Whh1f, b1f, Wih1r, Whh1r, b1r, nullptr, h2last);
  fc_kernel<<<dim3((BB * NCLS + 255) / 256), dim3(256), 0, stream>>>(
      h2last, fcw, fcb, (float*)d_out);

  // ---- diagnostics (results discarded; d_out/h1/h2last untouched) ----
  diag_clock<<<dim3(32), dim3(64), 0, stream>>>(x, dead);
  diag_sync<<<dim3(32), dim3(512), 0, stream>>>(x, gsink);
  diag_trans<<<dim3(32), dim3(512), 0, stream>>>(x, dead);
}

// Round 6
// 1230.479 us; speedup vs baseline: 8.4420x; 8.4420x over previous
//
#include <hip/hip_runtime.h>
#include <hip/hip_bf16.h>
#include <type_traits>

typedef short short8 __attribute__((ext_vector_type(8)));
typedef short short4v __attribute__((ext_vector_type(4)));
typedef float f32x4 __attribute__((ext_vector_type(4)));
typedef __bf16 bf16x8 __attribute__((ext_vector_type(8)));

#define DEVI static __device__ __forceinline__

#if __has_builtin(__builtin_amdgcn_exp2f)
#define EXP2(x) __builtin_amdgcn_exp2f(x)
#else
#define EXP2(x) exp2f(x)
#endif
#if __has_builtin(__builtin_amdgcn_rcpf)
#define RCP(x) __builtin_amdgcn_rcpf(x)
#else
#define RCP(x) (1.0f / (x))
#endif

static constexpr int BB = 256, TT = 512, DIN0 = 40, HH = 128, NCLS = 7;
static constexpr float L2E = 1.44269504088896f;

DEVI short f2b(float x) {
  union { __hip_bfloat16 h; short s; } u;
  u.h = __float2bfloat16(x);
  return u.s;
}
DEVI bf16x8 as_bf(short8 s) { return __builtin_bit_cast(bf16x8, s); }
DEVI float b2f(short s) {
  union { unsigned u; float f; } v;
  v.u = ((unsigned)(unsigned short)s) << 16;
  return v.f;
}

// lgkm-only barrier: global loads/stores stay in flight across it.
DEVI void bar_lgkm() {
  asm volatile("s_waitcnt lgkmcnt(0)\n\ts_barrier" ::: "memory");
}

// Montgomery batched reciprocal: r[i]=1/d[i], 1 rcp + 9 mul. d in [1, 1+2^30].
DEVI f32x4 inv4(f32x4 d) {
  float p1 = d[0] * d[1];
  float p2 = p1 * d[2];
  float p3 = p2 * d[3];
  float R = RCP(p3);
  f32x4 r;
  r[3] = R * p2;
  float R2 = R * d[3];
  r[2] = R2 * p1;
  float R1 = R2 * d[2];
  r[1] = R1 * d[0];
  r[0] = R1 * d[1];
  return r;
}

// ===================== Layer-0 recurrence =====================
// One WG = (dir, 16-batch tile). W register-resident (no occupancy arg ->
// 256-VGPR budget). h & x in conflict-free subtiled LDS [koct][bcol][8]:
// a wave's frag read is 1024B contiguous.
__global__ __launch_bounds__(512) void rec0(
    const float* __restrict__ x0,
    const float* __restrict__ Wih_f, const float* __restrict__ Whh_f,
    const float* __restrict__ b_f, const float* __restrict__ Wih_r,
    const float* __restrict__ Whh_r, const float* __restrict__ b_r,
    short* __restrict__ h1_out) {
  __shared__ short Hb[2][16][16][8];  // [buf][koct][bcol][8]
  __shared__ short X2[2][8][16][8];   // [buf][koct][bcol][8], K0=64

  const int tid = threadIdx.x, w = tid >> 6, lane = tid & 63;
  const int lg = lane >> 4, bcol = lane & 15;
  const int dir = blockIdx.x & 1, b0 = (blockIdx.x >> 1) * 16;
  const int j0 = w * 16 + lg * 4;
  const float* __restrict__ Wih = dir ? Wih_r : Wih_f;
  const float* __restrict__ Whh = dir ? Whh_r : Whh_f;
  const float* __restrict__ bias = dir ? b_r : b_f;
  auto tmap = [&](int s) { return dir ? (TT - 1 - s) : s; };

  // weights -> A-frags (row=lane&15, k=lg*8+e), pre-scaled:
  // i,f,o by -log2e (sigmoid via exp2); g by +2*log2e (tanh via exp2)
  short8 wx[4][2], wh[4][4];
  f32x4 bq[4];
#pragma unroll
  for (int q = 0; q < 4; ++q) {
    const float scale = (q == 2) ? (2.0f * L2E) : (-L2E);
    const int m = q * HH + w * 16 + bcol;
#pragma unroll
    for (int kk = 0; kk < 2; ++kk) {
      short8 f;
#pragma unroll
      for (int e = 0; e < 8; ++e) {
        const int k = kk * 32 + lg * 8 + e;
        float v = (k < DIN0) ? Wih[(size_t)m * DIN0 + k] : 0.0f;
        f[e] = f2b(v * scale);
      }
      wx[q][kk] = f;
    }
#pragma unroll
    for (int kk = 0; kk < 4; ++kk) {
      short8 f;
#pragma unroll
      for (int e = 0; e < 8; ++e)
        f[e] = f2b(Whh[(size_t)m * HH + kk * 32 + lg * 8 + e] * scale);
      wh[q][kk] = f;
    }
#pragma unroll
    for (int r = 0; r < 4; ++r) bq[q][r] = bias[q * HH + j0 + r] * scale;
  }

  for (int i = tid; i < 2 * 16 * 16 * 4; i += 512) ((int*)Hb)[i] = 0;
  for (int i = tid; i < 2 * 8 * 16 * 4; i += 512) ((int*)X2)[i] = 0;
  __syncthreads();

  auto load_x = [&](int s) -> f32x4 {
    f32x4 v = {0.f, 0.f, 0.f, 0.f};
    if (tid < 160) {
      int ss = (s < TT) ? s : (TT - 1);
      v = *(const f32x4*)(x0 + ((size_t)(b0 + tid / 10) * TT + tmap(ss)) * DIN0 + (tid % 10) * 4);
    }
    return v;
  };
  auto stage_x = [&](int buf, const f32x4& v) {
    if (tid < 160) {
      short4v o;
      o[0] = f2b(v[0]); o[1] = f2b(v[1]); o[2] = f2b(v[2]); o[3] = f2b(v[3]);
      const int row = tid / 10, c4 = tid % 10;
      *(short4v*)&X2[buf][c4 >> 1][row][(c4 & 1) * 4] = o;
    }
  };
  auto prefill = [&](f32x4* acc, int p) {
#pragma unroll
    for (int kk = 0; kk < 2; ++kk) {
      const bf16x8 bx = as_bf(*(const short8*)&X2[p][kk * 4 + lg][bcol][0]);
#pragma unroll
      for (int q = 0; q < 4; ++q)
        acc[q] = __builtin_amdgcn_mfma_f32_16x16x32_bf16(
            as_bf(wx[q][kk]), bx, (kk == 0) ? bq[q] : acc[q], 0, 0, 0);
    }
  };

  f32x4 cst = {0.f, 0.f, 0.f, 0.f};
  auto cell = [&](f32x4* a, int cur, int s) {
    f32x4 Ei, Ef, Eg, Eo;
#pragma unroll
    for (int r = 0; r < 4; ++r) {
      Ei[r] = EXP2(fminf(a[0][r], 30.f));
      Ef[r] = EXP2(fminf(a[1][r], 30.f));
      Eg[r] = EXP2(fminf(a[2][r], 30.f));
      Eo[r] = EXP2(fminf(a[3][r], 30.f));
    }
    const f32x4 one = {1.f, 1.f, 1.f, 1.f};
    f32x4 si = inv4(one + Ei), sf = inv4(one + Ef);
    f32x4 gd = inv4(one + Eg), so = inv4(one + Eo);
    f32x4 Ec;
#pragma unroll
    for (int r = 0; r < 4; ++r) {
      float tg = 1.f - 2.f * gd[r];
      cst[r] = sf[r] * cst[r] + si[r] * tg;
      Ec[r] = EXP2(fminf(cst[r] * (2.f * L2E), 30.f));
    }
    f32x4 cd = inv4(one + Ec);
    short4v hp;
#pragma unroll
    for (int r = 0; r < 4; ++r) hp[r] = f2b(so[r] * (1.f - 2.f * cd[r]));
    *(short4v*)&Hb[cur ^ 1][j0 >> 3][bcol][j0 & 7] = hp;
    *(short4v*)(h1_out + (((size_t)(b0 + bcol) * TT + tmap(s)) << 8) + dir * HH + j0) = hp;
  };

  stage_x(0, load_x(0));
  stage_x(1, load_x(1));
  f32x4 xst = load_x(2);
  __syncthreads();
  f32x4 accA[4], accB[4];
  prefill(accA, 0);
  bar_lgkm();  // X[0] reads done before step 0 overwrites X[0]

  auto stepf = [&](int s, int cur, f32x4* acc, f32x4* accN) {
#pragma unroll
    for (int kk = 0; kk < 4; ++kk) {
      const bf16x8 bh = as_bf(*(const short8*)&Hb[cur][kk * 4 + lg][bcol][0]);
#pragma unroll
      for (int q = 0; q < 4; ++q)
        acc[q] = __builtin_amdgcn_mfma_f32_16x16x32_bf16(as_bf(wh[q][kk]), bh, acc[q], 0, 0, 0);
    }
    cell(acc, cur, s);
    stage_x(cur, xst);       // x(s+2) -> X[cur]
    xst = load_x(s + 3);     // background load, ~2 steps of slack
    prefill(accN, cur ^ 1);  // acc(s+1) = bias + W_ih @ x(s+1), off-chain
    bar_lgkm();
  };
  for (int s = 0; s < TT; s += 2) {
    stepf(s, 0, accA, accB);
    stepf(s + 1, 1, accB, accA);
  }
}

// ===================== Layer-1 input projection (parallel GEMM) =====================
// pre[dir][bt][t][w][q*256 + (lg*16+bcol)*4 + r] = scale_q * (W_ih1 @ h1 + b1),
// written in MFMA C-fragment order so rec1's loads are 1KB-coalesced.
template <typename PT>
__global__ __launch_bounds__(512) void pre1(
    const short* __restrict__ h1, const float* __restrict__ Wih_f,
    const float* __restrict__ b_f, const float* __restrict__ Wih_r,
    const float* __restrict__ b_r, PT* __restrict__ pre) {
  __shared__ short X[16 * 256];  // 8KB, XOR-swizzled rows
  const int tid = threadIdx.x, w = tid >> 6, lane = tid & 63;
  const int lg = lane >> 4, bcol = lane & 15;
  const int gid = blockIdx.x;
  const int dir = gid & 1, tc = (gid >> 1) & 63, bt = gid >> 7;
  const float* __restrict__ Wih = dir ? Wih_r : Wih_f;
  const float* __restrict__ bias = dir ? b_r : b_f;
  const int b0 = bt * 16;

  short8 wx[4][8];
  f32x4 bq[4];
#pragma unroll
  for (int q = 0; q < 4; ++q) {
    const float scale = (q == 2) ? (2.0f * L2E) : (-L2E);
    const int m = q * HH + w * 16 + bcol;
#pragma unroll
    for (int kk = 0; kk < 8; ++kk) {
      short8 f;
#pragma unroll
      for (int e = 0; e < 8; ++e)
        f[e] = f2b(Wih[(size_t)m * 256 + kk * 32 + lg * 8 + e] * scale);
      wx[q][kk] = f;
    }
#pragma unroll
    for (int r = 0; r < 4; ++r) bq[q][r] = bias[q * HH + w * 16 + lg * 4 + r] * scale;
  }

  const int srow = tid >> 5, sch = tid & 31;
  for (int i = 0; i < 8; ++i) {
    const int t = tc * 8 + i;
    short8 v = *(const short8*)(h1 + (((size_t)(b0 + srow) * TT + t) << 8) + sch * 8);
    *(short8*)((char*)X + srow * 512 + ((sch * 16) ^ ((srow & 7) << 4))) = v;
    __syncthreads();
    f32x4 acc[4] = {bq[0], bq[1], bq[2], bq[3]};
#pragma unroll
    for (int kk = 0; kk < 8; ++kk) {
      const bf16x8 bx = as_bf(*(const short8*)((const char*)X + bcol * 512 +
                                               ((kk * 64 + lg * 16) ^ ((bcol & 7) << 4))));
#pragma unroll
      for (int q = 0; q < 4; ++q)
        acc[q] = __builtin_amdgcn_mfma_f32_16x16x32_bf16(as_bf(wx[q][kk]), bx, acc[q], 0, 0, 0);
    }
    PT* op = pre + ((((size_t)dir * 16 + bt) * TT + t) * 8 + w) * 1024 +
             (size_t)(lg * 16 + bcol) * 4;
#pragma unroll
    for (int q = 0; q < 4; ++q) {
      if constexpr (std::is_same_v<PT, float>) {
        *(f32x4*)(op + q * 256) = acc[q];
      } else {
        short4v o;
        o[0] = f2b(acc[q][0]); o[1] = f2b(acc[q][1]);
        o[2] = f2b(acc[q][2]); o[3] = f2b(acc[q][3]);
        *(short4v*)(op + q * 256) = o;
      }
    }
    __syncthreads();  // reads done before next iter overwrites X
  }
}

// ===================== Layer-1 recurrence (lean) =====================
template <typename PT>
__global__ __launch_bounds__(512) void rec1(
    const PT* __restrict__ pre, const float* __restrict__ Whh_f,
    const float* __restrict__ Whh_r, float* __restrict__ h2last) {
  __shared__ short Hb[2][16][16][8];
  const int tid = threadIdx.x, w = tid >> 6, lane = tid & 63;
  const int lg = lane >> 4, bcol = lane & 15;
  const int dir = blockIdx.x & 1, bt = blockIdx.x >> 1;
  const int b0 = bt * 16, j0 = w * 16 + lg * 4;
  const float* __restrict__ Whh = dir ? Whh_r : Whh_f;
  auto tmap = [&](int s) { return dir ? (TT - 1 - s) : s; };

  short8 wh[4][4];
#pragma unroll
  for (int q = 0; q < 4; ++q) {
    const float scale = (q == 2) ? (2.0f * L2E) : (-L2E);
    const int m = q * HH + w * 16 + bcol;
#pragma unroll
    for (int kk = 0; kk < 4; ++kk) {
      short8 f;
#pragma unroll
      for (int e = 0; e < 8; ++e)
        f[e] = f2b(Whh[(size_t)m * HH + kk * 32 + lg * 8 + e] * scale);
      wh[q][kk] = f;
    }
  }
  for (int i = tid; i < 2 * 16 * 16 * 4; i += 512) ((int*)Hb)[i] = 0;
  __syncthreads();

  const size_t laneoff = (size_t)(lg * 16 + bcol) * 4;
  auto loadp = [&](f32x4* p, int s) {
    int ss = (s < TT) ? s : (TT - 1);
    const PT* base = pre + ((((size_t)dir * 16 + bt) * TT + tmap(ss)) * 8 + w) * 1024 + laneoff;
#pragma unroll
    for (int q = 0; q < 4; ++q) {
      if constexpr (std::is_same_v<PT, float>) {
        p[q] = *(const f32x4*)(base + q * 256);
      } else {
        short4v v = *(const short4v*)(base + q * 256);
        p[q][0] = b2f(v[0]); p[q][1] = b2f(v[1]);
        p[q][2] = b2f(v[2]); p[q][3] = b2f(v[3]);
      }
    }
  };

  f32x4 cst = {0.f, 0.f, 0.f, 0.f};
  auto stepf = [&](int s, int cur, f32x4* pX) {
    f32x4 acc[4] = {pX[0], pX[1], pX[2], pX[3]};
#pragma unroll
    for (int kk = 0; kk < 4; ++kk) {
      const bf16x8 bh = as_bf(*(const short8*)&Hb[cur][kk * 4 + lg][bcol][0]);
#pragma unroll
      for (int q = 0; q < 4; ++q)
        acc[q] = __builtin_amdgcn_mfma_f32_16x16x32_bf16(as_bf(wh[q][kk]), bh, acc[q], 0, 0, 0);
    }
    f32x4 Ei, Ef, Eg, Eo;
#pragma unroll
    for (int r = 0; r < 4; ++r) {
      Ei[r] = EXP2(fminf(acc[0][r], 30.f));
      Ef[r] = EXP2(fminf(acc[1][r], 30.f));
      Eg[r] = EXP2(fminf(acc[2][r], 30.f));
      Eo[r] = EXP2(fminf(acc[3][r], 30.f));
    }
    const f32x4 one = {1.f, 1.f, 1.f, 1.f};
    f32x4 si = inv4(one + Ei), sf = inv4(one + Ef);
    f32x4 gd = inv4(one + Eg), so = inv4(one + Eo);
    f32x4 Ec;
#pragma unroll
    for (int r = 0; r < 4; ++r) {
      float tg = 1.f - 2.f * gd[r];
      cst[r] = sf[r] * cst[r] + si[r] * tg;
      Ec[r] = EXP2(fminf(cst[r] * (2.f * L2E), 30.f));
    }
    f32x4 cd = inv4(one + Ec);
    short4v hp;
    f32x4 hf;
#pragma unroll
    for (int r = 0; r < 4; ++r) {
      float hv = so[r] * (1.f - 2.f * cd[r]);
      hf[r] = hv;
      hp[r] = f2b(hv);
    }
    *(short4v*)&Hb[cur ^ 1][j0 >> 3][bcol][j0 & 7] = hp;
    if ((dir == 0 && s == TT - 1) || (dir == 1 && s == 0))
      *(f32x4*)(h2last + ((size_t)(b0 + bcol) << 8) + dir * HH + j0) = hf;
    loadp(pX, s + 2);  // refill freed regs for step s+2
    bar_lgkm();
  };

  f32x4 pA[4], pB[4];
  loadp(pA, 0);
  loadp(pB, 1);
  for (int s = 0; s < TT; s += 2) {
    stepf(s, 0, pA);
    stepf(s + 1, 1, pB);
  }
}

// ===================== Layer-1 fused fallback (small workspace) =====================
// x (=h1, 256-wide) staged via LDS double-buffer, XOR-swizzled; W_ih1 + W_hh1
// register-resident (192 VGPR of frags; full 256-VGPR budget available).
__global__ __launch_bounds__(512) void rec1_fused(
    const short* __restrict__ h1, const float* __restrict__ Wih_f,
    const float* __restrict__ Whh_f, const float* __restrict__ b_f,
    const float* __restrict__ Wih_r, const float* __restrict__ Whh_r,
    const float* __restrict__ b_r, float* __restrict__ h2last) {
  __shared__ short Hb[2][16][16][8];
  __shared__ char Xraw[16384];

  const int tid = threadIdx.x, w = tid >> 6, lane = tid & 63;
  const int lg = lane >> 4, bcol = lane & 15;
  const int dir = blockIdx.x & 1, b0 = (blockIdx.x >> 1) * 16;
  const int j0 = w * 16 + lg * 4;
  const float* __restrict__ Wih = dir ? Wih_r : Wih_f;
  const float* __restrict__ Whh = dir ? Whh_r : Whh_f;
  const float* __restrict__ bias = dir ? b_r : b_f;
  auto tmap = [&](int s) { return dir ? (TT - 1 - s) : s; };

  short8 wx[4][8], wh[4][4];
  f32x4 bq[4];
#pragma unroll
  for (int q = 0; q < 4; ++q) {
    const float scale = (q == 2) ? (2.0f * L2E) : (-L2E);
    const int m = q * HH + w * 16 + bcol;
#pragma unroll
    for (int kk = 0; kk < 8; ++kk) {
      short8 f;
#pragma unroll
      for (int e = 0; e < 8; ++e)
        f[e] = f2b(Wih[(size_t)m * 256 + kk * 32 + lg * 8 + e] * scale);
      wx[q][kk] = f;
    }
#pragma unroll
    for (int kk = 0; kk < 4; ++kk) {
      short8 f;
#pragma unroll
      for (int e = 0; e < 8; ++e)
        f[e] = f2b(Whh[(size_t)m * HH + kk * 32 + lg * 8 + e] * scale);
      wh[q][kk] = f;
    }
#pragma unroll
    for (int r = 0; r < 4; ++r) bq[q][r] = bias[q * HH + j0 + r] * scale;
  }
  for (int i = tid; i < 2 * 16 * 16 * 4; i += 512) ((int*)Hb)[i] = 0;
  __syncthreads();

  const int xr1 = tid >> 5;
  const int xcb = ((tid << 4) ^ (((tid >> 5) & 7) << 4)) & 511;
  auto ldx = [&](int p, int kk) -> short8 {
    int byte = ((bcol << 9) + (kk << 6) + (lg << 4)) ^ ((bcol & 7) << 4);
    return *(const short8*)(Xraw + p * 8192 + byte);
  };
  auto ldg = [&](int s) -> short8 {
    int ss = (s < TT) ? s : (TT - 1);
    return *(const short8*)((const char*)h1 + (((size_t)(b0 + xr1) * TT + tmap(ss)) << 9) + xcb);
  };

  {
    short8 v0 = ldg(0), v1 = ldg(1);
    *(short8*)(Xraw + tid * 16) = v0;
    *(short8*)(Xraw + 8192 + tid * 16) = v1;
  }
  short8 xstage = ldg(2);
  __syncthreads();

  f32x4 acc[4] = {bq[0], bq[1], bq[2], bq[3]};
#pragma unroll
  for (int kk = 0; kk < 8; ++kk) {
    bf16x8 bx = as_bf(ldx(0, kk));
#pragma unroll
    for (int q = 0; q < 4; ++q)
      acc[q] = __builtin_amdgcn_mfma_f32_16x16x32_bf16(as_bf(wx[q][kk]), bx, acc[q], 0, 0, 0);
  }
  bar_lgkm();

  f32x4 cst = {0.f, 0.f, 0.f, 0.f};
  auto stepf = [&](int s, int buf) {
    *(short8*)(Xraw + buf * 8192 + tid * 16) = xstage;  // x(s+2)
    xstage = ldg(s + 3);
#pragma unroll
    for (int kk = 0; kk < 4; ++kk) {
      bf16x8 bh = as_bf(*(const short8*)&Hb[buf][kk * 4 + lg][bcol][0]);
#pragma unroll
      for (int q = 0; q < 4; ++q)
        acc[q] = __builtin_amdgcn_mfma_f32_16x16x32_bf16(as_bf(wh[q][kk]), bh, acc[q], 0, 0, 0);
    }
    f32x4 Ei, Ef, Eg, Eo;
#pragma unroll
    for (int r = 0; r < 4; ++r) {
      Ei[r] = EXP2(fminf(acc[0][r], 30.f));
      Ef[r] = EXP2(fminf(acc[1][r], 30.f));
      Eg[r] = EXP2(fminf(acc[2][r], 30.f));
      Eo[r] = EXP2(fminf(acc[3][r], 30.f));
    }
    const f32x4 one = {1.f, 1.f, 1.f, 1.f};
    f32x4 si = inv4(one + Ei), sf = inv4(one + Ef);
    f32x4 gd = inv4(one + Eg), so = inv4(one + Eo);
    f32x4 Ec;
#pragma unroll
    for (int r = 0; r < 4; ++r) {
      float tg = 1.f - 2.f * gd[r];
      cst[r] = sf[r] * cst[r] + si[r] * tg;
      Ec[r] = EXP2(fminf(cst[r] * (2.f * L2E), 30.f));
    }
    f32x4 cd = inv4(one + Ec);
    short4v hp;
    f32x4 hf;
#pragma unroll
    for (int r = 0; r < 4; ++r) {
      float hv = so[r] * (1.f - 2.f * cd[r]);
      hf[r] = hv;
      hp[r] = f2b(hv);
    }
    *(short4v*)&Hb[buf ^ 1][j0 >> 3][bcol][j0 & 7] = hp;
    if ((dir == 0 && s == TT - 1) || (dir == 1 && s == 0))
      *(f32x4*)(h2last + ((size_t)(b0 + bcol) << 8) + dir * HH + j0) = hf;
    // tail prefill for s+1 from X[buf^1] = x(s+1)
#pragma unroll
    for (int q = 0; q < 4; ++q) acc[q] = bq[q];
#pragma unroll
    for (int kk = 0; kk < 8; ++kk) {
      bf16x8 bx = as_bf(ldx(buf ^ 1, kk));
#pragma unroll
      for (int q = 0; q < 4; ++q)
        acc[q] = __builtin_amdgcn_mfma_f32_16x16x32_bf16(as_bf(wx[q][kk]), bx, acc[q], 0, 0, 0);
    }
    bar_lgkm();
  };
  for (int s = 0; s < TT; s += 2) {
    stepf(s, 0);
    stepf(s + 1, 1);
  }
}

__global__ void fc_kernel(const float* __restrict__ h2last,
                          const float* __restrict__ fcw,
                          const float* __restrict__ fcb,
                          float* __restrict__ out) {
  const int gid = blockIdx.x * blockDim.x + threadIdx.x;
  if (gid >= BB * NCLS) return;
  const int b = gid / NCLS, n = gid % NCLS;
  const float* hp = h2last + (size_t)b * 256;
  const float* wp = fcw + (size_t)n * 256;
  float s = fcb[n];
#pragma unroll 8
  for (int j = 0; j < 256; ++j) s = fmaf(hp[j], wp[j], s);
  out[gid] = s;
}

extern "C" void kernel_launch(void* const* d_in, const int* in_sizes, int n_in,
                              void* d_out, int out_size, void* d_ws, size_t ws_size,
                              hipStream_t stream) {
  const float* x     = (const float*)d_in[0];
  const float* Wih0f = (const float*)d_in[1];
  const float* Whh0f = (const float*)d_in[2];
  const float* b0f   = (const float*)d_in[3];
  const float* Wih0r = (const float*)d_in[4];
  const float* Whh0r = (const float*)d_in[5];
  const float* b0r   = (const float*)d_in[6];
  const float* Wih1f = (const float*)d_in[7];
  const float* Whh1f = (const float*)d_in[8];
  const float* b1f   = (const float*)d_in[9];
  const float* Wih1r = (const float*)d_in[10];
  const float* Whh1r = (const float*)d_in[11];
  const float* b1r   = (const float*)d_in[12];
  const float* fcw   = (const float*)d_in[13];
  const float* fcb   = (const float*)d_in[14];

  short* h1 = (short*)d_ws;                               // [B][T][256] bf16, 64MB
  float* h2last = (float*)((char*)d_ws + (64ull << 20));  // [B][256] f32
  char* prebuf = (char*)d_ws + (64ull << 20) + (1ull << 20);

  const size_t preElems = 2ull * 16 * TT * 8 * 1024;  // 134M elems
  const size_t baseBytes = (64ull << 20) + (1ull << 20);

  rec0<<<dim3(32), dim3(512), 0, stream>>>(
      x, Wih0f, Whh0f, b0f, Wih0r, Whh0r, b0r, h1);

  if (ws_size >= baseBytes + preElems * 4) {
    float* pre = (float*)prebuf;
    pre1<float><<<dim3(2048), dim3(512), 0, stream>>>(h1, Wih1f, b1f, Wih1r, b1r, pre);
    rec1<float><<<dim3(32), dim3(512), 0, stream>>>(pre, Whh1f, Whh1r, h2last);
  } else if (ws_size >= baseBytes + preElems * 2) {
    short* pre = (short*)prebuf;
    pre1<short><<<dim3(2048), dim3(512), 0, stream>>>(h1, Wih1f, b1f, Wih1r, b1r, pre);
    rec1<short><<<dim3(32), dim3(512), 0, stream>>>(pre, Whh1f, Whh1r, h2last);
  } else {
    rec1_fused<<<dim3(32), dim3(512), 0, stream>>>(
        h1, Wih1f, Whh1f, b1f, Wih1r, Whh1r, b1r, h2last);
  }

  fc_kernel<<<dim3((BB * NCLS + 255) / 256), dim3(256), 0, stream>>>(
      h2last, fcw, fcb, (float*)d_out);
}